// Round 8
// baseline (314.130 us; speedup 1.0000x reference)
//
#include <hip/hip_runtime.h>
#include <hip/hip_fp16.h>

namespace {

constexpr int kFeat = 32;
constexpr int kNA = 64;
constexpr int kNE = 32;
constexpr int kGridElems = kFeat * kNA * kNE;   // 65536
constexpr int kPoleElems = kFeat * 2;           // 64
constexpr int kCols = kNA * kNE;                // 2048 grid columns
constexpr int kColS = kCols;                    // pole-south column index
constexpr int kColN = kCols + 1;                // pole-north column index
constexpr int kTotCols = kCols + 2;             // 2050

constexpr float kPi  = 3.14159265358979323846f;
constexpr float kPi2 = 1.57079632679489661923f;
constexpr float kOmegaAz = 0.09817477042468103f;   // 2*pi/64
constexpr float kOmegaEl = 0.09519977738150889f;   // pi/33
constexpr float kInvOmegaAz = 10.18591635788130f;  // 64/(2*pi)
constexpr float kInvOmegaEl = 10.50422624406509f;  // 33/pi
constexpr float kInvSinAz = 10.20229703f;          // 1/sin(2*pi/64)
constexpr float kInvSinEl = 10.52010966f;          // 1/sin(pi/33)

// Prepass: grid [F][A][E] fp32 -> gt [A*E + 2][F] fp16 (a feature column is
// one contiguous 64B cache line); poles appended as columns 2048/2049.
__global__ __launch_bounds__(256) void transpose_grid_h(
    const float* __restrict__ g, const float* __restrict__ poles,
    __half* __restrict__ gt) {
  int idx = blockIdx.x * 256 + threadIdx.x;
  if (idx < kGridElems) {
    int f = idx >> 11;       // / (NA*NE)
    int ae = idx & 2047;     // a*NE + e
    gt[ae * kFeat + f] = __float2half(g[idx]);
  }
  if (idx < kPoleElems) {
    int f = idx >> 1;
    int p = idx & 1;
    gt[(kCols + p) * kFeat + f] = __float2half(poles[idx]);
  }
}

struct PointSetup {
  int col_bl, col_br, col_tl, col_tr;
  float a1, a2, b1, b2;
};

__device__ __forceinline__ PointSetup setup_point(float az, float el) {
  PointSetup s;
  // azimuth bucket: ar = smallest k with tick_az[k] >= az; ticks at -pi + k*omega
  float ta = (az + kPi) * kInvOmegaAz;
  int ar0 = (int)ceilf(ta);
  int al = ar0 - 1;
  int ar = (ar0 >= kNA) ? 0 : ar0;
  if (al < 0) al = kNA - 1;
  float theta_a = az - (-kPi + (float)al * kOmegaAz);
  float w1a = __sinf(kOmegaAz - theta_a) * kInvSinAz;
  float w2a = __sinf(theta_a) * kInvSinAz;

  // elevation: er = searchsorted(interior ticks at -pi/2 + (k+1)*omega_el)
  float ue = (el + kPi2) * kInvOmegaEl;
  int er = (int)ceilf(ue) - 1;
  er = min(max(er, 0), kNE);
  bool south = (er == 0);
  bool north = (er == kNE);
  int eil = min(max(er - 1, 0), kNE - 1);
  int eir = min(er, kNE - 1);
  float base = south ? -kPi2 : (-kPi2 + (float)(eil + 1) * kOmegaEl);
  float theta_e = el - base;
  float w1e = __sinf(kOmegaEl - theta_e) * kInvSinEl;
  float w2e = __sinf(theta_e) * kInvSinEl;

  s.col_bl = al * kNE + eil;
  s.col_br = ar * kNE + eil;
  s.col_tl = al * kNE + eir;
  s.col_tr = ar * kNE + eir;
  s.a1 = w1e * w1a; s.a2 = w1e * w2a;
  s.b1 = w2e * w1a; s.b2 = w2e * w2a;
  // Pole redirect: exact pole value via two identical half-weight columns
  // (NORMALIZED=False, weights need not sum to 1).
  if (south) {
    s.col_bl = kColS; s.col_br = kColS;
    s.a1 = 0.5f * w1e; s.a2 = s.a1;
  }
  if (north) {
    s.col_tl = kColN; s.col_tr = kColN;
    s.b1 = 0.5f * w2e; s.b2 = s.b1;
  }
  return s;
}

// Ownership interp (R4 store path + full-point ownership):
//  - thread t owns point base+t ENTIRELY: 1 setup (not 4x redundant),
//    2 fully-coalesced pts loads (not 8 partially-broadcast),
//    16 uint4 gathers = 4 whole 64B columns. Per-point TA request count is
//    identical to R4 (16 requests/point); quarters q=1..3 of a column are
//    guaranteed L1 hits (a 64B column sits inside one 128B line).
//  - LDS staging tile[f][t]: lane-stride 4B per feature row -> perfectly
//    conflict-free ds_writes (R4's scattered pattern was up to 4-way).
//  - flush phase is EXACTLY R4's proven champion: per wave-store 1 KB fully
//    contiguous, 128B-line-complete, default-cached (NT refuted in R1/R7).
constexpr int kTile = 256;               // points per block
constexpr int kTileFloats = kFeat * kTile;   // 8192 floats = 32 KiB LDS

__global__ __launch_bounds__(256) void interp_o(
    const float* __restrict__ pts, const __half* __restrict__ gt,
    float* __restrict__ out, int n) {
  __shared__ float tile[kTileFloats];    // [feat][point], row-major
  const int base = blockIdx.x * kTile;
  const int rem = min(kTile, n - base);
  const size_t sn = (size_t)n;
  const int t = threadIdx.x;

  if (t < rem) {
    const int i = base + t;
    const float az = pts[i];
    const float el = pts[n + i];
    PointSetup s = setup_point(az, el);

    const uint4* cbl = (const uint4*)(gt + s.col_bl * kFeat);
    const uint4* cbr = (const uint4*)(gt + s.col_br * kFeat);
    const uint4* ctl = (const uint4*)(gt + s.col_tl * kFeat);
    const uint4* ctr = (const uint4*)(gt + s.col_tr * kFeat);

    union H8 { uint4 u; __half2 h[4]; };
    H8 bl[4], br[4], tl[4], tr[4];
#pragma unroll
    for (int q = 0; q < 4; ++q) {        // issue all 16 loads up front
      bl[q].u = cbl[q];
      br[q].u = cbr[q];
      tl[q].u = ctl[q];
      tr[q].u = ctr[q];
    }

#pragma unroll
    for (int q = 0; q < 4; ++q) {        // quarter q = feats 8q .. 8q+7
#pragma unroll
      for (int h = 0; h < 4; ++h) {      // half2 h within quarter
        float2 vbl = __half22float2(bl[q].h[h]);
        float2 vbr = __half22float2(br[q].h[h]);
        float2 vtl = __half22float2(tl[q].h[h]);
        float2 vtr = __half22float2(tr[q].h[h]);
        const int f = 8 * q + 2 * h;
        tile[(f + 0) * kTile + t] =
            s.a1 * vbl.x + s.a2 * vbr.x + s.b1 * vtl.x + s.b2 * vtr.x;
        tile[(f + 1) * kTile + t] =
            s.a1 * vbl.y + s.a2 * vbr.y + s.b1 * vtl.y + s.b2 * vtr.y;
      }
    }
  }

  __syncthreads();

  // ---- flush phase: LDS tile -> global, 1 KB contiguous per wave-store ----
  if (rem == kTile) {
#pragma unroll
    for (int r = 0; r < 8; ++r) {
      int u = t + 256 * r;
      int row = u >> 6;          // 64 lanes of a wave share one row
      int c4 = (u & 63) * 4;     // point offset within tile
      uint4 v = *(const uint4*)(tile + row * kTile + c4);
      *(uint4*)(out + (size_t)row * sn + base + c4) = v;
    }
  } else {
    // last partial tile: guarded element stores
    for (int r = 0; r < 8; ++r) {
      int u = t + 256 * r;
      int row = u >> 6;
      int c4 = (u & 63) * 4;
      float* o = out + (size_t)row * sn + base;
      for (int e = 0; e < 4; ++e) {
        int p = c4 + e;
        if (p < rem) o[p] = tile[row * kTile + p];
      }
    }
  }
}

// Fallback if the workspace is too small for the transposed fp16 grid:
// gather directly from the [F][A][E] layout (scalar strided loads).
__global__ __launch_bounds__(256) void interp_d(
    const float* __restrict__ pts, const float* __restrict__ g,
    const float* __restrict__ poles, float* __restrict__ out, int n) {
  int i = blockIdx.x * 256 + threadIdx.x;
  if (i >= n) return;
  float az = pts[i];
  float el = pts[n + i];
  PointSetup s = setup_point(az, el);

  float a1 = s.a1, a2 = s.a2, b1 = s.b1, b2 = s.b2;
  float pw0 = 0.0f, pw1 = 0.0f;
  if (s.col_bl == kColS) { pw0 = a1 + a2; a1 = 0.0f; a2 = 0.0f; }
  if (s.col_tl == kColN) { pw1 = b1 + b2; b1 = 0.0f; b2 = 0.0f; }

  const float* gbl = g + (s.col_bl < kCols ? s.col_bl : 0);
  const float* gbr = g + (s.col_br < kCols ? s.col_br : 0);
  const float* gtl = g + (s.col_tl < kCols ? s.col_tl : 0);
  const float* gtr = g + (s.col_tr < kCols ? s.col_tr : 0);
  size_t sn = (size_t)n;
#pragma unroll 8
  for (int f = 0; f < kFeat; ++f) {
    float v = a1 * gbl[f * kCols] + a2 * gbr[f * kCols]
            + b1 * gtl[f * kCols] + b2 * gtr[f * kCols]
            + pw0 * poles[f * 2 + 0] + pw1 * poles[f * 2 + 1];
    out[(size_t)f * sn + i] = v;
  }
}

}  // namespace

extern "C" void kernel_launch(void* const* d_in, const int* in_sizes, int n_in,
                              void* d_out, int out_size, void* d_ws, size_t ws_size,
                              hipStream_t stream) {
  (void)n_in; (void)out_size;
  const float* pts   = (const float*)d_in[0];
  const float* grid  = (const float*)d_in[1];
  const float* poles = (const float*)d_in[2];
  float* out = (float*)d_out;
  int n = in_sizes[0] / 2;

  size_t need = (size_t)(kTotCols * kFeat) * sizeof(__half);
  if (ws_size >= need) {
    __half* gt = (__half*)d_ws;
    transpose_grid_h<<<(kGridElems + 255) / 256, 256, 0, stream>>>(grid, poles, gt);
    int blocks = (n + kTile - 1) / kTile;
    interp_o<<<blocks, 256, 0, stream>>>(pts, gt, out, n);
  } else {
    int blocks = (n + 255) / 256;
    interp_d<<<blocks, 256, 0, stream>>>(pts, grid, poles, out, n);
  }
}

// Round 9
// 285.127 us; speedup vs baseline: 1.1017x; 1.1017x over previous
//
#include <hip/hip_runtime.h>
#include <hip/hip_fp16.h>

namespace {

constexpr int kFeat = 32;
constexpr int kNA = 64;
constexpr int kNE = 32;
constexpr int kGridElems = kFeat * kNA * kNE;   // 65536
constexpr int kPoleElems = kFeat * 2;           // 64
constexpr int kCols = kNA * kNE;                // 2048 grid columns
constexpr int kColS = kCols;                    // pole-south column index
constexpr int kColN = kCols + 1;                // pole-north column index
constexpr int kTotCols = kCols + 2;             // 2050

constexpr float kPi  = 3.14159265358979323846f;
constexpr float kPi2 = 1.57079632679489661923f;
constexpr float kOmegaAz = 0.09817477042468103f;   // 2*pi/64
constexpr float kOmegaEl = 0.09519977738150889f;   // pi/33
constexpr float kInvOmegaAz = 10.18591635788130f;  // 64/(2*pi)
constexpr float kInvOmegaEl = 10.50422624406509f;  // 33/pi
constexpr float kInvSinAz = 10.20229703f;          // 1/sin(2*pi/64)
constexpr float kInvSinEl = 10.52010966f;          // 1/sin(pi/33)

// Prepass: grid [F][A][E] fp32 -> gt [A*E + 2][F] fp16 (a feature column is
// one contiguous 64B cache line); poles appended as columns 2048/2049.
__global__ __launch_bounds__(256) void transpose_grid_h(
    const float* __restrict__ g, const float* __restrict__ poles,
    __half* __restrict__ gt) {
  int idx = blockIdx.x * 256 + threadIdx.x;
  if (idx < kGridElems) {
    int f = idx >> 11;       // / (NA*NE)
    int ae = idx & 2047;     // a*NE + e
    gt[ae * kFeat + f] = __float2half(g[idx]);
  }
  if (idx < kPoleElems) {
    int f = idx >> 1;
    int p = idx & 1;
    gt[(kCols + p) * kFeat + f] = __float2half(poles[idx]);
  }
}

struct PointSetup {
  int col_bl, col_br, col_tl, col_tr;
  float a1, a2, b1, b2;
};

__device__ __forceinline__ PointSetup setup_point(float az, float el) {
  PointSetup s;
  // azimuth bucket: ar = smallest k with tick_az[k] >= az; ticks at -pi + k*omega
  float ta = (az + kPi) * kInvOmegaAz;
  int ar0 = (int)ceilf(ta);
  int al = ar0 - 1;
  int ar = (ar0 >= kNA) ? 0 : ar0;
  if (al < 0) al = kNA - 1;
  float theta_a = az - (-kPi + (float)al * kOmegaAz);
  float w1a = __sinf(kOmegaAz - theta_a) * kInvSinAz;
  float w2a = __sinf(theta_a) * kInvSinAz;

  // elevation: er = searchsorted(interior ticks at -pi/2 + (k+1)*omega_el)
  float ue = (el + kPi2) * kInvOmegaEl;
  int er = (int)ceilf(ue) - 1;
  er = min(max(er, 0), kNE);
  bool south = (er == 0);
  bool north = (er == kNE);
  int eil = min(max(er - 1, 0), kNE - 1);
  int eir = min(er, kNE - 1);
  float base = south ? -kPi2 : (-kPi2 + (float)(eil + 1) * kOmegaEl);
  float theta_e = el - base;
  float w1e = __sinf(kOmegaEl - theta_e) * kInvSinEl;
  float w2e = __sinf(theta_e) * kInvSinEl;

  s.col_bl = al * kNE + eil;
  s.col_br = ar * kNE + eil;
  s.col_tl = al * kNE + eir;
  s.col_tr = ar * kNE + eir;
  s.a1 = w1e * w1a; s.a2 = w1e * w2a;
  s.b1 = w2e * w1a; s.b2 = w2e * w2a;
  // Pole redirect: exact pole value via two identical half-weight columns
  // (NORMALIZED=False, weights need not sum to 1).
  if (south) {
    s.col_bl = kColS; s.col_br = kColS;
    s.a1 = 0.5f * w1e; s.a2 = s.a1;
  }
  if (north) {
    s.col_tl = kColN; s.col_tr = kColN;
    s.b1 = 0.5f * w2e; s.b2 = s.b1;
  }
  return s;
}

// R4 champion structure + shuffle-deduplicated setup.
//  - Gather shape is EXACTLY R4's (load-bearing per R8's regression): for a
//    point, its 4 j-lanes read consecutive 16B quarters of each 64B column ->
//    16 distinct lines per gather instr (R8's own-point layout hit 64).
//  - Setup dedup: lane l computes setup for p_own = w*16 + 64*(l>>4) + (l&15)
//    (exactly the 64 points wave w processes). Per c-iter, the point
//    p = w*16 + 64c + (l>>2) is owned by lane c*16 + (l>>2); its 8 fields
//    arrive via __shfl (32 bpermutes replace ~3 redundant setup_points:
//    12 transcendentals + ~135 VALU). Setups are computed with a clamped
//    index so all 64 lanes stay shfl-active; gather/write are guarded.
//  - pts loads once per point (coalesced), not 4x broadcast.
//  - LDS tile + 1 KB-per-wave-store flush: bit-for-bit R4 (NT refuted twice).
constexpr int kTile = 256;               // points per block
constexpr int kTileFloats = kFeat * kTile;   // 8192 floats = 32 KiB LDS

__global__ __launch_bounds__(256) void interp_s(
    const float* __restrict__ pts, const __half* __restrict__ gt,
    float* __restrict__ out, int n) {
  __shared__ float tile[kTileFloats];    // [feat][point], row-major
  const int base = blockIdx.x * kTile;
  const int rem = min(kTile, n - base);
  const size_t sn = (size_t)n;
  const int t = threadIdx.x;
  const int w = t >> 6;                  // wave 0..3
  const int l = t & 63;                  // lane 0..63

  // ---- setup phase: one setup per point, computed by its owner lane ----
  const int p_own = w * 16 + 64 * (l >> 4) + (l & 15);
  const int pc = min(p_own, rem - 1);    // clamp keeps all lanes shfl-active
  const float az = pts[base + pc];
  const float el = pts[n + base + pc];
  const PointSetup so = setup_point(az, el);

  const int j = l & 3;
  const int off = j * 8;

  // ---- compute phase: 4 c-iters, R4 slot mapping ----
#pragma unroll
  for (int c = 0; c < 4; ++c) {
    const int src = c * 16 + (l >> 2);   // owner lane of this iter's point
    const int cbl = __shfl(so.col_bl, src);
    const int cbr = __shfl(so.col_br, src);
    const int ctl = __shfl(so.col_tl, src);
    const int ctr = __shfl(so.col_tr, src);
    const float a1 = __shfl(so.a1, src);
    const float a2 = __shfl(so.a2, src);
    const float b1 = __shfl(so.b1, src);
    const float b2 = __shfl(so.b2, src);
    const int p = w * 16 + 64 * c + (l >> 2);
    if (p < rem) {
      union H8 { uint4 u; __half2 h[4]; };
      H8 bl, br, tl, tr;
      bl.u = *(const uint4*)(gt + cbl * kFeat + off);
      br.u = *(const uint4*)(gt + cbr * kFeat + off);
      tl.u = *(const uint4*)(gt + ctl * kFeat + off);
      tr.u = *(const uint4*)(gt + ctr * kFeat + off);
      float* dst = tile + (8 * j) * kTile + p;   // rows 8j..8j+7, column p
#pragma unroll
      for (int q = 0; q < 4; ++q) {
        float2 vbl = __half22float2(bl.h[q]);
        float2 vbr = __half22float2(br.h[q]);
        float2 vtl = __half22float2(tl.h[q]);
        float2 vtr = __half22float2(tr.h[q]);
        dst[(2 * q + 0) * kTile] =
            a1 * vbl.x + a2 * vbr.x + b1 * vtl.x + b2 * vtr.x;
        dst[(2 * q + 1) * kTile] =
            a1 * vbl.y + a2 * vbr.y + b1 * vtl.y + b2 * vtr.y;
      }
    }
  }

  __syncthreads();

  // ---- flush phase: LDS tile -> global, 1 KB contiguous per wave-store ----
  if (rem == kTile) {
#pragma unroll
    for (int r = 0; r < 8; ++r) {
      int u = t + 256 * r;
      int row = u >> 6;          // 64 lanes of a wave share one row
      int c4 = (u & 63) * 4;     // point offset within tile
      uint4 v = *(const uint4*)(tile + row * kTile + c4);
      *(uint4*)(out + (size_t)row * sn + base + c4) = v;
    }
  } else {
    // last partial tile: guarded element stores
    for (int r = 0; r < 8; ++r) {
      int u = t + 256 * r;
      int row = u >> 6;
      int c4 = (u & 63) * 4;
      float* o = out + (size_t)row * sn + base;
      for (int e = 0; e < 4; ++e) {
        int p = c4 + e;
        if (p < rem) o[p] = tile[row * kTile + p];
      }
    }
  }
}

// Fallback if the workspace is too small for the transposed fp16 grid:
// gather directly from the [F][A][E] layout (scalar strided loads).
__global__ __launch_bounds__(256) void interp_d(
    const float* __restrict__ pts, const float* __restrict__ g,
    const float* __restrict__ poles, float* __restrict__ out, int n) {
  int i = blockIdx.x * 256 + threadIdx.x;
  if (i >= n) return;
  float az = pts[i];
  float el = pts[n + i];
  PointSetup s = setup_point(az, el);

  float a1 = s.a1, a2 = s.a2, b1 = s.b1, b2 = s.b2;
  float pw0 = 0.0f, pw1 = 0.0f;
  if (s.col_bl == kColS) { pw0 = a1 + a2; a1 = 0.0f; a2 = 0.0f; }
  if (s.col_tl == kColN) { pw1 = b1 + b2; b1 = 0.0f; b2 = 0.0f; }

  const float* gbl = g + (s.col_bl < kCols ? s.col_bl : 0);
  const float* gbr = g + (s.col_br < kCols ? s.col_br : 0);
  const float* gtl = g + (s.col_tl < kCols ? s.col_tl : 0);
  const float* gtr = g + (s.col_tr < kCols ? s.col_tr : 0);
  size_t sn = (size_t)n;
#pragma unroll 8
  for (int f = 0; f < kFeat; ++f) {
    float v = a1 * gbl[f * kCols] + a2 * gbr[f * kCols]
            + b1 * gtl[f * kCols] + b2 * gtr[f * kCols]
            + pw0 * poles[f * 2 + 0] + pw1 * poles[f * 2 + 1];
    out[(size_t)f * sn + i] = v;
  }
}

}  // namespace

extern "C" void kernel_launch(void* const* d_in, const int* in_sizes, int n_in,
                              void* d_out, int out_size, void* d_ws, size_t ws_size,
                              hipStream_t stream) {
  (void)n_in; (void)out_size;
  const float* pts   = (const float*)d_in[0];
  const float* grid  = (const float*)d_in[1];
  const float* poles = (const float*)d_in[2];
  float* out = (float*)d_out;
  int n = in_sizes[0] / 2;

  size_t need = (size_t)(kTotCols * kFeat) * sizeof(__half);
  if (ws_size >= need) {
    __half* gt = (__half*)d_ws;
    transpose_grid_h<<<(kGridElems + 255) / 256, 256, 0, stream>>>(grid, poles, gt);
    int blocks = (n + kTile - 1) / kTile;
    interp_s<<<blocks, 256, 0, stream>>>(pts, gt, out, n);
  } else {
    int blocks = (n + 255) / 256;
    interp_d<<<blocks, 256, 0, stream>>>(pts, grid, poles, out, n);
  }
}